// Round 4
// baseline (160.368 us; speedup 1.0000x reference)
//
#include <hip/hip_runtime.h>
#include <cstdint>
#include <cstddef>

#define WDIM 1600
#define BDIM 4
#define HDIM 900
#define NV4  225   // float4s per column (900/4)
#define NCHV 4     // ceil(225/64)
#define QCAP 96    // max valid radar entries per column (mean ~27, sigma ~5.1)
#define KBIG (4 * HDIM)
#define BW   6     // query batch width
#define NWAVE 2    // waves (columns) per block

// Phase 1: one wave per (w,b) column.
__global__ __launch_bounds__(64 * NWAVE, 8) void radar_place_kernel(
    const float* __restrict__ radar, const float* __restrict__ mde,
    float* __restrict__ colout /* (W*B, H) */, int direct, float* __restrict__ out)
{
    __shared__ __align__(16) float s_col[NWAVE][HDIM];
    __shared__ float s_qd[NWAVE][QCAP];
    __shared__ int   s_qy[NWAVE][QCAP];
    __shared__ int   s_by[NWAVE][QCAP];

    const int wave = threadIdx.x >> 6;
    const int lane = threadIdx.x & 63;
    const int lane4 = lane << 2;
    const int colid = blockIdx.x * NWAVE + wave;   // grid exactly W*B/NWAVE blocks
    const float4* mde4   = (const float4*)mde   + (long)colid * NV4;
    const float4* radar4 = (const float4*)radar + (long)colid * NV4;

    float*  col  = s_col[wave];
    float4* col4 = (float4*)col;
    float*  qd   = s_qd[wave];
    int*    qy   = s_qy[wave];
    int*    by   = s_by[wave];

    const unsigned long long below = (1ull << lane) - 1ull;

    // --- Stage A: vector loads, query compaction, col zero-init ---
    float m[16];
    bool hm = false;
    int Q = 0;
#pragma unroll
    for (int c = 0; c < NCHV; ++c) {
        int i4 = c * 64 + lane;
        bool in = (i4 < NV4);
        float4 mv = in ? mde4[i4] : make_float4(0.f, 0.f, 0.f, 0.f);
        m[c * 4 + 0] = (mv.x != 0.f) ? mv.x : 1e30f;
        m[c * 4 + 1] = (mv.y != 0.f) ? mv.y : 1e30f;
        m[c * 4 + 2] = (mv.z != 0.f) ? mv.z : 1e30f;
        m[c * 4 + 3] = (mv.w != 0.f) ? mv.w : 1e30f;
        hm = hm || (mv.x != 0.f) || (mv.y != 0.f) || (mv.z != 0.f) || (mv.w != 0.f);

        if (in) col4[i4] = make_float4(0.f, 0.f, 0.f, 0.f);

        float4 rv = in ? radar4[i4] : make_float4(0.f, 0.f, 0.f, 0.f);
        unsigned long long b0 = __ballot(rv.x != 0.f);
        unsigned long long b1 = __ballot(rv.y != 0.f);
        unsigned long long b2 = __ballot(rv.z != 0.f);
        unsigned long long b3 = __ballot(rv.w != 0.f);
        int pos = Q + __popcll(b0 & below) + __popcll(b1 & below)
                    + __popcll(b2 & below) + __popcll(b3 & below);
        int y0 = i4 * 4;
        if (rv.x != 0.f) { if (pos < QCAP) { qd[pos] = rv.x; qy[pos] = y0;     } pos++; }
        if (rv.y != 0.f) { if (pos < QCAP) { qd[pos] = rv.y; qy[pos] = y0 + 1; } pos++; }
        if (rv.z != 0.f) { if (pos < QCAP) { qd[pos] = rv.z; qy[pos] = y0 + 2; } pos++; }
        if (rv.w != 0.f) { if (pos < QCAP) { qd[pos] = rv.w; qy[pos] = y0 + 3; } pos++; }
        Q += __popcll(b0) + __popcll(b1) + __popcll(b2) + __popcll(b3);
    }
    if (Q > QCAP) Q = QCAP;
    const bool has_mde = (__ballot(hm) != 0ull);

    // --- Stage B: batched argmin prepass (placement-independent) ---
    for (int t = 0; t < Q; t += BW) {
        float d[BW];
#pragma unroll
        for (int i = 0; i < BW; ++i) {
            int idx = (t + i < Q) ? (t + i) : (Q - 1);
            d[i] = qd[idx];                 // wave-uniform broadcast LDS read
        }
        float bd[BW], bo[BW];
        int bi[BW];
#pragma unroll
        for (int i = 0; i < BW; ++i) { bd[i] = 3.4e38f; bi[i] = 0; }
        // per-lane scan: yy ascending within lane -> strict < keeps first index
#pragma unroll
        for (int c = 0; c < NCHV; ++c) {
#pragma unroll
            for (int j = 0; j < 4; ++j) {
                float mm = m[c * 4 + j];
                int yy = c * 256 + lane4 + j;
#pragma unroll
                for (int i = 0; i < BW; ++i) {
                    float af = fabsf(mm - d[i]);
                    if (af < bd[i]) { bd[i] = af; bi[i] = yy; }
                }
            }
        }
#pragma unroll
        for (int i = 0; i < BW; ++i) bo[i] = bd[i];
        // f32 min butterfly (BW interleaved chains)
#pragma unroll
        for (int off = 32; off; off >>= 1)
#pragma unroll
            for (int i = 0; i < BW; ++i)
                bd[i] = fminf(bd[i], __shfl_xor(bd[i], off));
        // tie resolution: unique tied lane (common) -> single shfl; else index butterfly
#pragma unroll
        for (int i = 0; i < BW; ++i) {
            unsigned long long wm = __ballot(bo[i] == bd[i]);
            int res;
            if (__popcll(wm) == 1) {
                res = __shfl(bi[i], __ffsll(wm) - 1);
            } else {
                int c2 = (bo[i] == bd[i]) ? bi[i] : 0x7fffffff;
#pragma unroll
                for (int off = 32; off; off >>= 1) {
                    int v = __shfl_xor(c2, off);
                    c2 = (v < c2) ? v : c2;
                }
                res = c2;
            }
            if (lane == 0 && t + i < Q) by[t + i] = res;
        }
    }

    // occupancy bitmask: bit (c*4+j) of lane l <=> y = (c*64+l)*4+j occupied.
    // pre-set invalid tail slots (chunk 3, lane >= 33) as occupied.
    unsigned occ = (lane >= 33) ? 0xF000u : 0u;

    // --- Stage C: sequential placement (register occupancy, no LDS reads on probe) ---
    for (int q = 0; q < Q; ++q) {
        int best = has_mde ? by[q] : qy[q];   // wave-uniform broadcast LDS read
        float depth = qd[q];
        int bi4 = best >> 2, bj = best & 3;
        int bc = bi4 >> 6, bl = bi4 & 63;
        int bbit = bc * 4 + bj;
        unsigned long long bm = __ballot((occ >> bbit) & 1u);
        int final_y = best;
        if ((bm >> bl) & 1ull) {
            // slow path (rare): key = occ ? KBIG : 2|dy| + (dy<0); argmin, first index
            int bk = 0x7fffffff, bki = 0;
#pragma unroll
            for (int c = 0; c < NCHV; ++c) {
#pragma unroll
                for (int j = 0; j < 4; ++j) {
                    int yy = c * 256 + lane4 + j;
                    int o = (occ >> (c * 4 + j)) & 1u;
                    int dy = yy - best;
                    int ad = dy < 0 ? -dy : dy;
                    int key = o ? KBIG : (2 * ad + (dy < 0 ? 1 : 0));
                    if (key < bk) { bk = key; bki = yy; }
                }
            }
            int bko = bk;
#pragma unroll
            for (int off = 32; off; off >>= 1) {
                int v = __shfl_xor(bk, off);
                bk = (v < bk) ? v : bk;
            }
            int c2 = (bko == bk) ? bki : 0x7fffffff;
#pragma unroll
            for (int off = 32; off; off >>= 1) {
                int v = __shfl_xor(c2, off);
                c2 = (v < c2) ? v : c2;
            }
            final_y = (bk >= KBIG) ? best : c2;
        }
        // mark occupied + write depth
        int fi4 = final_y >> 2, fj = final_y & 3;
        int fc = fi4 >> 6, fl = fi4 & 63;
        if (lane == fl) occ |= (1u << (fc * 4 + fj));
        if (lane == 0) col[final_y] = depth;   // same-wave DS program order = RAW safe
    }

    // --- writeout ---
    if (direct) {
        int w_ = colid >> 2, b_ = colid & 3;
#pragma unroll
        for (int c = 0; c < NCHV; ++c) {
            int i4 = c * 64 + lane;
            if (i4 < NV4) {
                float4 v = col4[i4];
                int y = i4 * 4;
                out[((long)(b_ * HDIM + y + 0)) * WDIM + w_] = v.x;
                out[((long)(b_ * HDIM + y + 1)) * WDIM + w_] = v.y;
                out[((long)(b_ * HDIM + y + 2)) * WDIM + w_] = v.z;
                out[((long)(b_ * HDIM + y + 3)) * WDIM + w_] = v.w;
            }
        }
    } else {
        float4* colout4 = (float4*)colout + (long)colid * NV4;
#pragma unroll
        for (int c = 0; c < NCHV; ++c) {
            int i4 = c * 64 + lane;
            if (i4 < NV4) colout4[i4] = col4[i4];
        }
    }
}

// Phase 2: transpose (W*B, H) -> (B, H, W), fully coalesced both sides.
__global__ __launch_bounds__(256) void transpose_kernel(
    const float* __restrict__ colout, float* __restrict__ out)
{
    __shared__ float tile[32][33];
    const int b  = blockIdx.z;
    const int h0 = blockIdx.x * 32;
    const int w0 = blockIdx.y * 32;
    const int tx = threadIdx.x & 31;
    const int ty = threadIdx.x >> 5;  // 0..7
#pragma unroll
    for (int j = 0; j < 4; ++j) {
        int wl = ty + j * 8;
        int w = w0 + wl;
        int h = h0 + tx;
        float v = 0.0f;
        if (h < HDIM && w < WDIM) v = colout[((long)(w * BDIM + b)) * HDIM + h];
        tile[wl][tx] = v;
    }
    __syncthreads();
#pragma unroll
    for (int j = 0; j < 4; ++j) {
        int hl = ty + j * 8;
        int h = h0 + hl;
        int w = w0 + tx;
        if (h < HDIM && w < WDIM)
            out[((long)(b * HDIM + h)) * WDIM + w] = tile[tx][hl];
    }
}

extern "C" void kernel_launch(void* const* d_in, const int* in_sizes, int n_in,
                              void* d_out, int out_size, void* d_ws, size_t ws_size,
                              hipStream_t stream) {
    const float* radar = (const float*)d_in[0];
    const float* mde   = (const float*)d_in[1];
    float* out = (float*)d_out;
    float* ws  = (float*)d_ws;

    const size_t need = (size_t)WDIM * BDIM * HDIM * sizeof(float);
    const int direct = (ws_size < need) ? 1 : 0;

    hipLaunchKernelGGL(radar_place_kernel,
                       dim3(WDIM * BDIM / NWAVE), dim3(64 * NWAVE), 0, stream,
                       radar, mde, ws, direct, out);

    if (!direct) {
        dim3 g((HDIM + 31) / 32, WDIM / 32, BDIM);
        hipLaunchKernelGGL(transpose_kernel, g, dim3(256), 0, stream, ws, out);
    }
}

// Round 5
// 136.984 us; speedup vs baseline: 1.1707x; 1.1707x over previous
//
#include <hip/hip_runtime.h>
#include <cstdint>
#include <cstddef>

#define WDIM 1600
#define BDIM 4
#define HDIM 900
#define NV4  225   // float4s per column (900/4)
#define QCAP 96    // max valid radar entries per column (mean ~27, sigma ~5.1)
#define KBIG (4 * HDIM)
#define BW   6     // query batch width

// wave64 min via DPP: after the 6 steps lane 63 holds the full-wave min.
// Canonical GCN cross-lane reduction (row_shr 1/2/4/8, row_bcast15/31).
// old = v (lanes with invalid DPP source keep v => fminf(v,v) no-op).
#define DPP_MINF(v, ctrl)                                                  \
    v = fminf(v, __int_as_float(__builtin_amdgcn_update_dpp(               \
            __float_as_int(v), __float_as_int(v), ctrl, 0xf, 0xf, false)))

// Phase 1: one wave (= one block) per (w,b) column.
__global__ __launch_bounds__(64) void radar_place_kernel(
    const float* __restrict__ radar, const float* __restrict__ mde,
    float* __restrict__ colout /* (W*B, H) */, int direct, float* __restrict__ out)
{
    __shared__ __align__(16) float s_col[HDIM];
    __shared__ float s_qd[QCAP];
    __shared__ int   s_qy[QCAP];

    const int lane = threadIdx.x;          // 0..63, single wave per block
    const int colid = blockIdx.x;          // 0..W*B-1
    const float4* mde4   = (const float4*)mde   + (long)colid * NV4;
    const float4* radar4 = (const float4*)radar + (long)colid * NV4;
    float4* col4 = (float4*)s_col;

    const unsigned long long below = (1ull << lane) - 1ull;

    // --- A1: coalesced mde load -> stash raw into s_col (used as scratch) ---
    bool hm = false;
#pragma unroll
    for (int c = 0; c < 4; ++c) {
        int i4 = c * 64 + lane;
        if (i4 < NV4) {
            float4 mv = mde4[i4];
            hm = hm || (mv.x != 0.f) || (mv.y != 0.f) || (mv.z != 0.f) || (mv.w != 0.f);
            col4[i4] = mv;
        }
    }
    const bool has_mde = (__ballot(hm) != 0ull);

    // --- A2: radar load + ascending-y compaction into s_qd/s_qy ---
    int Q = 0;
#pragma unroll
    for (int c = 0; c < 4; ++c) {
        int i4 = c * 64 + lane;
        bool in = (i4 < NV4);
        float4 rv = in ? radar4[i4] : make_float4(0.f, 0.f, 0.f, 0.f);
        unsigned long long b0 = __ballot(rv.x != 0.f);
        unsigned long long b1 = __ballot(rv.y != 0.f);
        unsigned long long b2 = __ballot(rv.z != 0.f);
        unsigned long long b3 = __ballot(rv.w != 0.f);
        int pos = Q + __popcll(b0 & below) + __popcll(b1 & below)
                    + __popcll(b2 & below) + __popcll(b3 & below);
        int y0 = i4 * 4;
        if (rv.x != 0.f) { if (pos < QCAP) { s_qd[pos] = rv.x; s_qy[pos] = y0;     } pos++; }
        if (rv.y != 0.f) { if (pos < QCAP) { s_qd[pos] = rv.y; s_qy[pos] = y0 + 1; } pos++; }
        if (rv.z != 0.f) { if (pos < QCAP) { s_qd[pos] = rv.z; s_qy[pos] = y0 + 2; } pos++; }
        if (rv.w != 0.f) { if (pos < QCAP) { s_qd[pos] = rv.w; s_qy[pos] = y0 + 3; } pos++; }
        Q += __popcll(b0) + __popcll(b1) + __popcll(b2) + __popcll(b3);
    }
    if (Q > QCAP) Q = QCAP;

    __syncthreads();   // mde staged in s_col visible / ordered

    // --- A3: redistribute mde lane-major: lane l owns y = l*15 + k (900 = 60*15) ---
    float m[15];
    if (lane < 60) {
        int yb = lane * 15;
#pragma unroll
        for (int k = 0; k < 15; ++k) {
            float v = s_col[yb + k];       // addr = 15*l + k: 15 odd => conflict-free
            m[k] = (v != 0.f) ? v : 1e30f; // invalid mde -> BIG diff
        }
    } else {
#pragma unroll
        for (int k = 0; k < 15; ++k) m[k] = 1e30f;
    }

    __syncthreads();   // reads complete before zeroing (WAR)

    // --- A4: zero output column ---
#pragma unroll
    for (int c = 0; c < 4; ++c) {
        int i4 = c * 64 + lane;
        if (i4 < NV4) col4[i4] = make_float4(0.f, 0.f, 0.f, 0.f);
    }

    // occupancy: bit k of lane l <=> y = l*15+k occupied; lanes >= 60 inert
    unsigned occ = (lane >= 60) ? 0x7FFFu : 0u;

    // --- fused argmin + placement, BW queries per batch ---
    for (int t = 0; t < Q; t += BW) {
        float d[BW];
#pragma unroll
        for (int i = 0; i < BW; ++i) {
            int idx = (t + i < Q) ? (t + i) : (Q - 1);
            d[i] = s_qd[idx];              // wave-uniform broadcast LDS read
        }
        float bd[BW], bo[BW];
        int bik[BW];
#pragma unroll
        for (int i = 0; i < BW; ++i) { bd[i] = 3.4e38f; bik[i] = 0; }
        // per-lane scan over its 15 contiguous y: k ascending => first index kept
#pragma unroll
        for (int k = 0; k < 15; ++k) {
            float mm = m[k];
#pragma unroll
            for (int i = 0; i < BW; ++i) {
                float af = fabsf(mm - d[i]);
                if (af < bd[i]) { bd[i] = af; bik[i] = k; }
            }
        }
#pragma unroll
        for (int i = 0; i < BW; ++i) bo[i] = bd[i];
        // wave-wide f32 min via DPP (6 VALU steps, BW interleaved); min -> lane 63
#pragma unroll
        for (int i = 0; i < BW; ++i) DPP_MINF(bd[i], 0x111);
#pragma unroll
        for (int i = 0; i < BW; ++i) DPP_MINF(bd[i], 0x112);
#pragma unroll
        for (int i = 0; i < BW; ++i) DPP_MINF(bd[i], 0x114);
#pragma unroll
        for (int i = 0; i < BW; ++i) DPP_MINF(bd[i], 0x118);
#pragma unroll
        for (int i = 0; i < BW; ++i) DPP_MINF(bd[i], 0x142);
#pragma unroll
        for (int i = 0; i < BW; ++i) DPP_MINF(bd[i], 0x143);

        // --- per-query tie-break + placement ---
#pragma unroll
        for (int i = 0; i < BW; ++i) {
            if (t + i < Q) {
                int best;
                if (has_mde) {
                    float gm = __int_as_float(
                        __builtin_amdgcn_readlane(__float_as_int(bd[i]), 63));
                    // first lane holding global min; its first-k => global first y.
                    // (lanes 60-63 have bo ~1e30 > gm, never win when has_mde)
                    unsigned long long wm = __ballot(bo[i] == gm);
                    int win = __ffsll((long long)wm) - 1;
                    int kst = __shfl(bik[i], win);
                    best = win * 15 + kst;
                } else {
                    best = s_qy[t + i];
                }
                float depth = d[i];
                int sb = __builtin_amdgcn_readfirstlane(best);
                int bl = sb / 15, bk = sb % 15;
                unsigned long long bm = __ballot((occ >> bk) & 1u);
                int final_y = sb;
                if ((bm >> bl) & 1ull) {
                    // slow path (rare): key = occ ? KBIG : 2|dy|+(dy<0); argmin.
                    // key is injective below KBIG => unique winner lane.
                    int ko = 0x7fffffff, kk = 0;
#pragma unroll
                    for (int k = 0; k < 15; ++k) {
                        int yy = lane * 15 + k;
                        int o = (occ >> k) & 1;
                        int dy = yy - sb;
                        int ad = dy < 0 ? -dy : dy;
                        int key = o ? KBIG : (2 * ad + (dy < 0 ? 1 : 0));
                        if (key < ko) { ko = key; kk = k; }
                    }
                    int kmin = ko;
#pragma unroll
                    for (int off = 32; off; off >>= 1) {
                        int v = __shfl_xor(kmin, off);
                        kmin = (v < kmin) ? v : kmin;
                    }
                    if (kmin < KBIG) {
                        unsigned long long wm2 = __ballot(ko == kmin);
                        int w2 = __ffsll((long long)wm2) - 1;
                        int k2 = __shfl(kk, w2);
                        final_y = w2 * 15 + k2;
                    }
                }
                int sf = __builtin_amdgcn_readfirstlane(final_y);
                int fl = sf / 15, fk = sf % 15;
                if (lane == fl) occ |= (1u << fk);
                if (lane == 0) s_col[sf] = depth;  // same-wave DS order = RAW safe
            }
        }
    }

    __syncthreads();   // drain placement writes before readback

    // --- writeout ---
    if (direct) {
        int w_ = colid >> 2, b_ = colid & 3;
#pragma unroll
        for (int c = 0; c < 4; ++c) {
            int i4 = c * 64 + lane;
            if (i4 < NV4) {
                float4 v = col4[i4];
                int y = i4 * 4;
                out[((long)(b_ * HDIM + y + 0)) * WDIM + w_] = v.x;
                out[((long)(b_ * HDIM + y + 1)) * WDIM + w_] = v.y;
                out[((long)(b_ * HDIM + y + 2)) * WDIM + w_] = v.z;
                out[((long)(b_ * HDIM + y + 3)) * WDIM + w_] = v.w;
            }
        }
    } else {
        float4* colout4 = (float4*)colout + (long)colid * NV4;
#pragma unroll
        for (int c = 0; c < 4; ++c) {
            int i4 = c * 64 + lane;
            if (i4 < NV4) colout4[i4] = col4[i4];
        }
    }
}

// Phase 2: transpose (W*B, H) -> (B, H, W), fully coalesced both sides.
__global__ __launch_bounds__(256) void transpose_kernel(
    const float* __restrict__ colout, float* __restrict__ out)
{
    __shared__ float tile[32][33];
    const int b  = blockIdx.z;
    const int h0 = blockIdx.x * 32;
    const int w0 = blockIdx.y * 32;
    const int tx = threadIdx.x & 31;
    const int ty = threadIdx.x >> 5;  // 0..7
#pragma unroll
    for (int j = 0; j < 4; ++j) {
        int wl = ty + j * 8;
        int w = w0 + wl;
        int h = h0 + tx;
        float v = 0.0f;
        if (h < HDIM && w < WDIM) v = colout[((long)(w * BDIM + b)) * HDIM + h];
        tile[wl][tx] = v;
    }
    __syncthreads();
#pragma unroll
    for (int j = 0; j < 4; ++j) {
        int hl = ty + j * 8;
        int h = h0 + hl;
        int w = w0 + tx;
        if (h < HDIM && w < WDIM)
            out[((long)(b * HDIM + h)) * WDIM + w] = tile[tx][hl];
    }
}

extern "C" void kernel_launch(void* const* d_in, const int* in_sizes, int n_in,
                              void* d_out, int out_size, void* d_ws, size_t ws_size,
                              hipStream_t stream) {
    const float* radar = (const float*)d_in[0];
    const float* mde   = (const float*)d_in[1];
    float* out = (float*)d_out;
    float* ws  = (float*)d_ws;

    const size_t need = (size_t)WDIM * BDIM * HDIM * sizeof(float);
    const int direct = (ws_size < need) ? 1 : 0;

    hipLaunchKernelGGL(radar_place_kernel,
                       dim3(WDIM * BDIM), dim3(64), 0, stream,
                       radar, mde, ws, direct, out);

    if (!direct) {
        dim3 g((HDIM + 31) / 32, WDIM / 32, BDIM);
        hipLaunchKernelGGL(transpose_kernel, g, dim3(256), 0, stream, ws, out);
    }
}